// Round 1
// baseline (2563.389 us; speedup 1.0000x reference)
//
#include <hip/hip_runtime.h>

// ---------------------------------------------------------------------------
// CycleS loss on MI355X (gfx950).
// Pipeline:
//   1. normalize feat0/1/2 -> bf16 nf (4096x1024)
//   2. S01,S02,S12 = nf_i @ nf_j^T        (NT bf16 MFMA GEMM, K=1024)
//   3. per cycle-term X (3 pairs + 3 triples):
//        rowsum/colsum of exp(scale*X), reciprocal,
//        A = rowsoftmax(X), Bc = colsoftmax(X)  (bf16)
//        fused GEMM-reduce: M = A @ Bc^T -> diag, offdiag rowmax/colmax
//   4. triples: T1 = NT(S02,S12); T2 = NT(S01,S12^T); T3 = NT(S01^T,S02^T)
//   5. final: sum relu(max+0.5-diag) / (2*4096*3)
// ---------------------------------------------------------------------------

#define NN 4096
#define DD 1024
static constexpr float SCALE_F = 83.17766166719343f; // ln(4096)/0.1

typedef short  s16x8 __attribute__((ext_vector_type(8)));
typedef float  f32x4 __attribute__((ext_vector_type(4)));

__device__ __forceinline__ float bflo(unsigned w) { return __uint_as_float(w << 16); }
__device__ __forceinline__ float bfhi(unsigned w) { return __uint_as_float(w & 0xffff0000u); }
__device__ __forceinline__ unsigned short f2bf(float f) {
  unsigned u = __float_as_uint(f);
  u += 0x7fffu + ((u >> 16) & 1u);
  return (unsigned short)(u >> 16);
}
__device__ __forceinline__ unsigned pack2(float a, float b) {
  return (unsigned)f2bf(a) | ((unsigned)f2bf(b) << 16);
}
__device__ __forceinline__ void amaxf(float* a, float v) {
  atomicMax((int*)a, __float_as_int(v)); // valid: all values >= 0
}
__device__ __forceinline__ void gl_lds16(const void* g, void* l) {
  __builtin_amdgcn_global_load_lds(
      (const __attribute__((address_space(1))) void*)g,
      (__attribute__((address_space(3))) void*)l, 16, 0, 0);
}

// ---------------------------------------------------------------------------
__global__ __launch_bounds__(256) void cyc_zero(float* p, int n) {
  int i = blockIdx.x * 256 + threadIdx.x;
  if (i < n) p[i] = 0.f;
}

// row-normalize fp32 -> bf16. one block per row, 256 threads * float4
__global__ __launch_bounds__(256) void cyc_norm(const float* __restrict__ in,
                                                unsigned short* __restrict__ out) {
  int row = blockIdx.x, t = threadIdx.x;
  float4 v = *(const float4*)(in + (size_t)row * DD + t * 4);
  float ss = v.x * v.x + v.y * v.y + v.z * v.z + v.w * v.w;
  for (int o = 32; o > 0; o >>= 1) ss += __shfl_down(ss, o);
  __shared__ float red[4];
  if ((t & 63) == 0) red[t >> 6] = ss;
  __syncthreads();
  float tot = red[0] + red[1] + red[2] + red[3];
  float sc = 1.f / fmaxf(sqrtf(tot), 1e-12f);
  uint2 o;
  o.x = pack2(v.x * sc, v.y * sc);
  o.y = pack2(v.z * sc, v.w * sc);
  *(uint2*)(out + (size_t)row * DD + t * 4) = o;
}

// ---------------------------------------------------------------------------
// NT GEMM: C[4096][4096] = A[4096][KT] @ B[4096][KT]^T   (bf16 in, fp32 acc)
// m97 structure: 128x128 tile, BK=64, 4 waves (2x2), 4x4 16x16x32 frags/wave.
// REDUCE: skip C write; emit diag + offdiag row/col max (atomicMax).
template <int KT, bool REDUCE>
__global__ __launch_bounds__(256) void cyc_gemm(
    const unsigned short* __restrict__ A, const unsigned short* __restrict__ B,
    unsigned short* __restrict__ C, float* __restrict__ rowmax,
    float* __restrict__ colmax, float* __restrict__ diag) {
  __shared__ alignas(16) unsigned short As[128 * 64];
  __shared__ alignas(16) unsigned short Bs[128 * 64];
  __shared__ float redrow[128];
  __shared__ float redcol[128];

  int bid = blockIdx.x;
  int bm = bid >> 5, bn = bid & 31;
  int m0 = bm << 7, n0 = bn << 7;
  int t = threadIdx.x;
  int l = t & 63, w = t >> 6;
  int wr = w >> 1, wc = w & 1;
  int fr = l & 15, fq = l >> 4;

  f32x4 acc[4][4];
#pragma unroll
  for (int m = 0; m < 4; ++m)
#pragma unroll
    for (int n = 0; n < 4; ++n) acc[m][n] = (f32x4){0.f, 0.f, 0.f, 0.f};

  for (int k0 = 0; k0 < KT; k0 += 64) {
    __syncthreads(); // protect LDS from previous iteration's readers
#pragma unroll
    for (int i = 0; i < 4; ++i) {
      int lin = i * 256 + t;      // 16B chunk index 0..1023
      int r = lin >> 3;           // tile row 0..127
      int ce = (lin & 7) << 3;    // element col 0,8,..,56
      gl_lds16(A + (size_t)(m0 + r) * KT + k0 + ce, As + lin * 8);
      gl_lds16(B + (size_t)(n0 + r) * KT + k0 + ce, Bs + lin * 8);
    }
    __syncthreads(); // compiler emits vmcnt(0) drain before barrier
#pragma unroll
    for (int kk = 0; kk < 2; ++kk) {
      s16x8 af[4], bf_[4];
#pragma unroll
      for (int m = 0; m < 4; ++m)
        af[m] = *(const s16x8*)(As + (wr * 64 + m * 16 + fr) * 64 + kk * 32 + fq * 8);
#pragma unroll
      for (int n = 0; n < 4; ++n)
        bf_[n] = *(const s16x8*)(Bs + (wc * 64 + n * 16 + fr) * 64 + kk * 32 + fq * 8);
#pragma unroll
      for (int m = 0; m < 4; ++m)
#pragma unroll
        for (int n = 0; n < 4; ++n)
          acc[m][n] = __builtin_amdgcn_mfma_f32_16x16x32_bf16(af[m], bf_[n], acc[m][n], 0, 0, 0);
    }
  }

  if constexpr (!REDUCE) {
#pragma unroll
    for (int m = 0; m < 4; ++m)
#pragma unroll
      for (int n = 0; n < 4; ++n)
#pragma unroll
        for (int j = 0; j < 4; ++j) {
          int gr = m0 + wr * 64 + m * 16 + fq * 4 + j;
          int gc = n0 + wc * 64 + n * 16 + fr;
          C[(size_t)gr * NN + gc] = f2bf(acc[m][n][j]);
        }
  } else {
    if (t < 128) redrow[t] = 0.f;
    else redcol[t - 128] = 0.f;
    __syncthreads();
    // row maxes (offdiag; diag captured exactly once grid-wide)
#pragma unroll
    for (int m = 0; m < 4; ++m)
#pragma unroll
      for (int j = 0; j < 4; ++j) {
        int lr = wr * 64 + m * 16 + fq * 4 + j;
        int p = m0 + lr;
        float rm = 0.f;
#pragma unroll
        for (int n = 0; n < 4; ++n) {
          int q = n0 + wc * 64 + n * 16 + fr;
          float v = acc[m][n][j];
          if (p == q) { diag[p] = v; v = 0.f; }
          rm = fmaxf(rm, v);
        }
        rm = fmaxf(rm, __shfl_xor(rm, 1));
        rm = fmaxf(rm, __shfl_xor(rm, 2));
        rm = fmaxf(rm, __shfl_xor(rm, 4));
        rm = fmaxf(rm, __shfl_xor(rm, 8));
        if (fr == 0) amaxf(&redrow[lr], rm);
      }
    // col maxes
#pragma unroll
    for (int n = 0; n < 4; ++n) {
      int lc = wc * 64 + n * 16 + fr;
      int q = n0 + lc;
      float cm = 0.f;
#pragma unroll
      for (int m = 0; m < 4; ++m)
#pragma unroll
        for (int j = 0; j < 4; ++j) {
          int p = m0 + wr * 64 + m * 16 + fq * 4 + j;
          float v = acc[m][n][j];
          if (p == q) v = 0.f;
          cm = fmaxf(cm, v);
        }
      cm = fmaxf(cm, __shfl_xor(cm, 16));
      cm = fmaxf(cm, __shfl_xor(cm, 32));
      if (fq == 0) amaxf(&redcol[lc], cm);
    }
    __syncthreads();
    if (t < 128) amaxf(&rowmax[m0 + t], redrow[t]);
    else amaxf(&colmax[n0 + (t - 128)], redcol[t - 128]);
  }
}

// ---------------------------------------------------------------------------
// LDS-tiled transpose, bf16 4096x4096
__global__ __launch_bounds__(256) void cyc_trans(const unsigned short* __restrict__ in,
                                                 unsigned short* __restrict__ out) {
  __shared__ alignas(16) unsigned short tile[128][136];
  int bx = blockIdx.x & 31, by = blockIdx.x >> 5;
  int r0 = by << 7, c0 = bx << 7;
  int t = threadIdx.x;
#pragma unroll
  for (int i = 0; i < 8; ++i) {
    int lin = i * 256 + t;
    int r = lin >> 4;
    int c8 = (lin & 15) << 3;
    *(uint4*)(&tile[r][c8]) = *(const uint4*)(in + (size_t)(r0 + r) * NN + c0 + c8);
  }
  __syncthreads();
#pragma unroll
  for (int i = 0; i < 8; ++i) {
    int lin = i * 256 + t;
    int c = lin >> 4;
    int r8 = (lin & 15) << 3;
    unsigned short v[8];
#pragma unroll
    for (int j = 0; j < 8; ++j) v[j] = tile[r8 + j][c];
    uint4 o;
    o.x = (unsigned)v[0] | ((unsigned)v[1] << 16);
    o.y = (unsigned)v[2] | ((unsigned)v[3] << 16);
    o.z = (unsigned)v[4] | ((unsigned)v[5] << 16);
    o.w = (unsigned)v[6] | ((unsigned)v[7] << 16);
    *(uint4*)(out + (size_t)(c0 + c) * NN + r0 + r8) = o;
  }
}

// ---------------------------------------------------------------------------
__global__ __launch_bounds__(256) void cyc_rowsum(const unsigned short* __restrict__ X,
                                                  float* __restrict__ rs) {
  int row = blockIdx.x, t = threadIdx.x;
  const uint4* rp = (const uint4*)(X + (size_t)row * NN);
  float s = 0.f;
#pragma unroll
  for (int h = 0; h < 2; ++h) {
    uint4 u = rp[t + h * 256];
    s += __expf(SCALE_F * bflo(u.x)) + __expf(SCALE_F * bfhi(u.x));
    s += __expf(SCALE_F * bflo(u.y)) + __expf(SCALE_F * bfhi(u.y));
    s += __expf(SCALE_F * bflo(u.z)) + __expf(SCALE_F * bfhi(u.z));
    s += __expf(SCALE_F * bflo(u.w)) + __expf(SCALE_F * bfhi(u.w));
  }
  for (int o = 32; o > 0; o >>= 1) s += __shfl_down(s, o);
  __shared__ float red[4];
  if ((t & 63) == 0) red[t >> 6] = s;
  __syncthreads();
  if (t == 0) rs[row] = red[0] + red[1] + red[2] + red[3];
}

// grid (2, 256): block = 2048 cols x 16 rows, thread owns 8 cols
__global__ __launch_bounds__(256) void cyc_colsum(const unsigned short* __restrict__ X,
                                                  float* __restrict__ cs) {
  int t = threadIdx.x;
  int c0 = blockIdx.x * 2048 + t * 8;
  int r0 = blockIdx.y * 16;
  float a[8];
#pragma unroll
  for (int j = 0; j < 8; ++j) a[j] = 0.f;
  for (int r = 0; r < 16; ++r) {
    uint4 u = *(const uint4*)(X + (size_t)(r0 + r) * NN + c0);
    a[0] += __expf(SCALE_F * bflo(u.x)); a[1] += __expf(SCALE_F * bfhi(u.x));
    a[2] += __expf(SCALE_F * bflo(u.y)); a[3] += __expf(SCALE_F * bfhi(u.y));
    a[4] += __expf(SCALE_F * bflo(u.z)); a[5] += __expf(SCALE_F * bfhi(u.z));
    a[6] += __expf(SCALE_F * bflo(u.w)); a[7] += __expf(SCALE_F * bfhi(u.w));
  }
#pragma unroll
  for (int j = 0; j < 8; ++j) atomicAdd(&cs[c0 + j], a[j]);
}

__global__ __launch_bounds__(256) void cyc_inv(float* p) { // 8192 floats (rs+cs)
  int i = blockIdx.x * 256 + threadIdx.x;
  if (i < 2 * NN) p[i] = 1.f / p[i];
}

// A = rowsoftmax, Bc = colsoftmax (bf16), elementwise over X
__global__ __launch_bounds__(256) void cyc_abgen(const unsigned short* __restrict__ X,
                                                 const float* __restrict__ rinv,
                                                 const float* __restrict__ cinv,
                                                 unsigned short* __restrict__ A,
                                                 unsigned short* __restrict__ B) {
  size_t idx = (size_t)blockIdx.x * 256 + threadIdx.x;
  int row = (int)(idx >> 9);
  int c0 = ((int)idx & 511) << 3;
  size_t off = ((size_t)row << 12) + c0;
  uint4 u = *(const uint4*)(X + off);
  float ri = rinv[row];
  float4 ci0 = *(const float4*)(cinv + c0);
  float4 ci1 = *(const float4*)(cinv + c0 + 4);
  float e0 = __expf(SCALE_F * bflo(u.x)), e1 = __expf(SCALE_F * bfhi(u.x));
  float e2 = __expf(SCALE_F * bflo(u.y)), e3 = __expf(SCALE_F * bfhi(u.y));
  float e4 = __expf(SCALE_F * bflo(u.z)), e5 = __expf(SCALE_F * bfhi(u.z));
  float e6 = __expf(SCALE_F * bflo(u.w)), e7 = __expf(SCALE_F * bfhi(u.w));
  uint4 oa, ob;
  oa.x = pack2(e0 * ri, e1 * ri); oa.y = pack2(e2 * ri, e3 * ri);
  oa.z = pack2(e4 * ri, e5 * ri); oa.w = pack2(e6 * ri, e7 * ri);
  ob.x = pack2(e0 * ci0.x, e1 * ci0.y); ob.y = pack2(e2 * ci0.z, e3 * ci0.w);
  ob.z = pack2(e4 * ci1.x, e5 * ci1.y); ob.w = pack2(e6 * ci1.z, e7 * ci1.w);
  *(uint4*)(A + off) = oa;
  *(uint4*)(B + off) = ob;
}

// final scalar: sum over 6 terms of relu(rowmax+M-diag)+relu(colmax+M-diag)
__global__ __launch_bounds__(256) void cyc_loss(const float* __restrict__ arr,
                                                float* __restrict__ out) {
  int t = threadIdx.x;
  float s = 0.f;
  for (int term = 0; term < 6; ++term) {
    const float* base = arr + (size_t)term * 5 * NN;
    const float* rm = base + 2 * NN;
    const float* cm = base + 3 * NN;
    const float* dg = base + 4 * NN;
    for (int i = t; i < NN; i += 256) {
      float d = dg[i];
      s += fmaxf(rm[i] + 0.5f - d, 0.f) + fmaxf(cm[i] + 0.5f - d, 0.f);
    }
  }
  for (int o = 32; o > 0; o >>= 1) s += __shfl_down(s, o);
  __shared__ float red[4];
  if ((t & 63) == 0) red[t >> 6] = s;
  __syncthreads();
  if (t == 0) out[0] = (red[0] + red[1] + red[2] + red[3]) * (1.f / (2.f * NN * 3.f));
}

// ---------------------------------------------------------------------------
static void process_term(const unsigned short* X, int term, unsigned short* Abuf,
                         unsigned short* Bbuf, float* arr, hipStream_t s) {
  float* base = arr + (size_t)term * 5 * NN;
  float* rs = base;
  float* cs = base + NN;
  float* rmax = base + 2 * NN;
  float* cmax = base + 3 * NN;
  float* dg = base + 4 * NN;
  cyc_rowsum<<<NN, 256, 0, s>>>(X, rs);
  cyc_colsum<<<dim3(2, 256), 256, 0, s>>>(X, cs);
  cyc_inv<<<32, 256, 0, s>>>(rs); // inverts rs and cs (contiguous 8192)
  cyc_abgen<<<8192, 256, 0, s>>>(X, rs, cs, Abuf, Bbuf);
  cyc_gemm<NN, true><<<1024, 256, 0, s>>>(Abuf, Bbuf, nullptr, rmax, cmax, dg);
}

extern "C" void kernel_launch(void* const* d_in, const int* in_sizes, int n_in,
                              void* d_out, int out_size, void* d_ws, size_t ws_size,
                              hipStream_t stream) {
  (void)in_sizes; (void)n_in; (void)out_size; (void)ws_size;
  const float* f0 = (const float*)d_in[0];
  const float* f1 = (const float*)d_in[1];
  const float* f2 = (const float*)d_in[2];
  char* ws = (char*)d_ws;

  const size_t NF_ELEMS = (size_t)NN * DD;     // 4M shorts = 8 MB
  const size_t S_ELEMS = (size_t)NN * NN;      // 16M shorts = 32 MB
  unsigned short* NF0 = (unsigned short*)ws;
  unsigned short* NF1 = NF0 + NF_ELEMS;
  unsigned short* NF2 = NF1 + NF_ELEMS;
  unsigned short* SA = NF2 + NF_ELEMS; // S01
  unsigned short* SB = SA + S_ELEMS;   // S02
  unsigned short* SC = SB + S_ELEMS;   // S12
  unsigned short* TB = SC + S_ELEMS;   // scratch matrix
  unsigned short* AB = TB + S_ELEMS;   // A (rowsoftmax)
  unsigned short* BB = AB + S_ELEMS;   // Bc (colsoftmax)
  float* arr = (float*)(BB + S_ELEMS); // [6][5][4096] fp32
  float* out = (float*)d_out;

  cyc_zero<<<(6 * 5 * NN + 255) / 256, 256, 0, stream>>>(arr, 6 * 5 * NN);
  cyc_norm<<<NN, 256, 0, stream>>>(f0, NF0);
  cyc_norm<<<NN, 256, 0, stream>>>(f1, NF1);
  cyc_norm<<<NN, 256, 0, stream>>>(f2, NF2);

  // pair similarity matrices
  cyc_gemm<DD, false><<<1024, 256, 0, stream>>>(NF0, NF1, SA, nullptr, nullptr, nullptr);
  cyc_gemm<DD, false><<<1024, 256, 0, stream>>>(NF0, NF2, SB, nullptr, nullptr, nullptr);
  cyc_gemm<DD, false><<<1024, 256, 0, stream>>>(NF1, NF2, SC, nullptr, nullptr, nullptr);

  // pair terms
  process_term(SA, 0, AB, BB, arr, stream);
  process_term(SB, 1, AB, BB, arr, stream);
  process_term(SC, 2, AB, BB, arr, stream);

  // T1 = S02 @ S12^T = NT(SB, SC)
  cyc_gemm<NN, false><<<1024, 256, 0, stream>>>(SB, SC, TB, nullptr, nullptr, nullptr);
  process_term(TB, 3, AB, BB, arr, stream);

  // T2 = S01 @ S12 = NT(SA, S12^T): transpose SC -> TB, output into SC slot
  cyc_trans<<<1024, 256, 0, stream>>>(SC, TB);
  cyc_gemm<NN, false><<<1024, 256, 0, stream>>>(SA, TB, SC, nullptr, nullptr, nullptr);
  process_term(SC, 4, AB, BB, arr, stream);

  // T3 = S01^T @ S02 = NT(S01^T, S02^T): S10 -> TB, S20 -> AB, out into SA slot
  cyc_trans<<<1024, 256, 0, stream>>>(SA, TB);
  cyc_trans<<<1024, 256, 0, stream>>>(SB, AB);
  cyc_gemm<NN, false><<<1024, 256, 0, stream>>>(TB, AB, SA, nullptr, nullptr, nullptr);
  process_term(SA, 5, AB, BB, arr, stream);

  cyc_loss<<<1, 256, 0, stream>>>(arr, out);
}

// Round 2
// 1945.661 us; speedup vs baseline: 1.3175x; 1.3175x over previous
//
#include <hip/hip_runtime.h>

// ---------------------------------------------------------------------------
// CycleS loss on MI355X (gfx950).
// Round 2: 256x256-tile GEMM, BK=64, 8 waves, K-half LDS panels [256][32]
// (conflict-free ds_read_b128), 4 fine phases/K-tile with counted vmcnt(4)
// (never drain in main loop), setprio around MFMA clusters.
// ---------------------------------------------------------------------------

#define NN 4096
#define DD 1024
static constexpr float SCALE_F = 83.17766166719343f; // ln(4096)/0.1

typedef short  s16x8 __attribute__((ext_vector_type(8)));
typedef float  f32x4 __attribute__((ext_vector_type(4)));

__device__ __forceinline__ float bflo(unsigned w) { return __uint_as_float(w << 16); }
__device__ __forceinline__ float bfhi(unsigned w) { return __uint_as_float(w & 0xffff0000u); }
__device__ __forceinline__ unsigned short f2bf(float f) {
  unsigned u = __float_as_uint(f);
  u += 0x7fffu + ((u >> 16) & 1u);
  return (unsigned short)(u >> 16);
}
__device__ __forceinline__ unsigned pack2(float a, float b) {
  return (unsigned)f2bf(a) | ((unsigned)f2bf(b) << 16);
}
__device__ __forceinline__ void amaxf(float* a, float v) {
  atomicMax((int*)a, __float_as_int(v)); // valid: all values >= 0
}
__device__ __forceinline__ void gl_lds16(const void* g, void* l) {
  __builtin_amdgcn_global_load_lds(
      (const __attribute__((address_space(1))) void*)g,
      (__attribute__((address_space(3))) void*)l, 16, 0, 0);
}

// ---------------------------------------------------------------------------
__global__ __launch_bounds__(256) void cyc_zero(float* p, int n) {
  int i = blockIdx.x * 256 + threadIdx.x;
  if (i < n) p[i] = 0.f;
}

// row-normalize fp32 -> bf16. one block per row, 256 threads * float4
__global__ __launch_bounds__(256) void cyc_norm(const float* __restrict__ in,
                                                unsigned short* __restrict__ out) {
  int row = blockIdx.x, t = threadIdx.x;
  float4 v = *(const float4*)(in + (size_t)row * DD + t * 4);
  float ss = v.x * v.x + v.y * v.y + v.z * v.z + v.w * v.w;
  for (int o = 32; o > 0; o >>= 1) ss += __shfl_down(ss, o);
  __shared__ float red[4];
  if ((t & 63) == 0) red[t >> 6] = ss;
  __syncthreads();
  float tot = red[0] + red[1] + red[2] + red[3];
  float sc = 1.f / fmaxf(sqrtf(tot), 1e-12f);
  uint2 o;
  o.x = pack2(v.x * sc, v.y * sc);
  o.y = pack2(v.z * sc, v.w * sc);
  *(uint2*)(out + (size_t)row * DD + t * 4) = o;
}

// ---------------------------------------------------------------------------
// NT GEMM: C[4096][4096] = A[4096][KT] @ B[4096][KT]^T   (bf16 in, fp32 acc)
// 256x256 tile, BK=64 (two K-halves of 32), 8 waves (2Mx4N), 512 threads.
// LDS: LA/LB[dbuf][khalf][256][32] bf16 = 128 KB total. Counted-vmcnt pipe.
// REDUCE: skip C write; emit diag + offdiag row/col max (atomicMax).
template <int KT, bool REDUCE>
__global__ __launch_bounds__(512, 2) void cyc_gemm(
    const unsigned short* __restrict__ A, const unsigned short* __restrict__ B,
    unsigned short* __restrict__ C, float* __restrict__ rowmax,
    float* __restrict__ colmax, float* __restrict__ diag) {
  __shared__ alignas(16) unsigned short LA[2][2][256][32]; // 64 KB
  __shared__ alignas(16) unsigned short LB[2][2][256][32]; // 64 KB
  __shared__ float redrow[256];
  __shared__ float redcol[256];

  constexpr int NT = KT / 64;
  const int bid = blockIdx.x;
  const int bm = bid >> 4, bn = bid & 15;
  const int m0 = bm << 8, n0 = bn << 8;
  const int tid = threadIdx.x;
  const int l = tid & 63, w = tid >> 6;
  const int wm = w >> 2, wn = w & 3;
  const int fr = l & 15, fq = l >> 4;
  const int ar = wm * 128 + fr; // + m*16
  const int br = wn * 64 + fr;  // + n*16
  // staging geometry: chunk c = i*512+tid -> panel row c>>2, col8 (c&3)*8
  const int sr0 = tid >> 2, sc0 = (tid & 3) << 3;       // i=0
  const int sr1 = (512 + tid) >> 2, sc1 = sc0;          // i=1

  f32x4 acc[8][4];
#pragma unroll
  for (int m = 0; m < 8; ++m)
#pragma unroll
    for (int n = 0; n < 4; ++n) acc[m][n] = (f32x4){0.f, 0.f, 0.f, 0.f};
  s16x8 af[8], bfv[4];

#define STAGE_A(buf, kk, kbase)                                              \
  {                                                                          \
    gl_lds16(A + (size_t)(m0 + sr0) * KT + (kbase) + (kk) * 32 + sc0,        \
             &LA[buf][kk][sr0][sc0]);                                        \
    gl_lds16(A + (size_t)(m0 + sr1) * KT + (kbase) + (kk) * 32 + sc1,        \
             &LA[buf][kk][sr1][sc1]);                                        \
  }
#define STAGE_B(buf, kk, kbase)                                              \
  {                                                                          \
    gl_lds16(B + (size_t)(n0 + sr0) * KT + (kbase) + (kk) * 32 + sc0,        \
             &LB[buf][kk][sr0][sc0]);                                        \
    gl_lds16(B + (size_t)(n0 + sr1) * KT + (kbase) + (kk) * 32 + sc1,        \
             &LB[buf][kk][sr1][sc1]);                                        \
  }
#define LOAD_A(buf, kk)                                                      \
  _Pragma("unroll") for (int m = 0; m < 8; ++m) af[m] =                      \
      *(const s16x8*)&LA[buf][kk][ar + m * 16][fq * 8];
#define LOAD_B(buf, kk, n) bfv[n] = *(const s16x8*)&LB[buf][kk][br + (n)*16][fq * 8];
#define MFMA_PAIR(na, nb)                                                    \
  {                                                                          \
    _Pragma("unroll") for (int m = 0; m < 8; ++m) acc[m][na] =               \
        __builtin_amdgcn_mfma_f32_16x16x32_bf16(af[m], bfv[na], acc[m][na], 0, 0, 0); \
    _Pragma("unroll") for (int m = 0; m < 8; ++m) acc[m][nb] =               \
        __builtin_amdgcn_mfma_f32_16x16x32_bf16(af[m], bfv[nb], acc[m][nb], 0, 0, 0); \
  }
#define BAR() __builtin_amdgcn_s_barrier()
#define WAIT_LGKM() asm volatile("s_waitcnt lgkmcnt(0)" ::: "memory")
#define VM(n) asm volatile("s_waitcnt vmcnt(" #n ")" ::: "memory")

  // prologue: stage tile 0 fully (A0,B0,A1,B1), wait for k-half 0 panels
  STAGE_A(0, 0, 0) STAGE_B(0, 0, 0) STAGE_A(0, 1, 0) STAGE_B(0, 1, 0)
  VM(4);
  BAR();

#pragma unroll 1
  for (int ti = 0; ti < NT - 1; ++ti) {
    const int p = ti & 1;
    const int kn = (ti + 1) * 64;
    // ---- phase 1: kk0, n{0,1}; stage A0(next)
    LOAD_A(p, 0) LOAD_B(p, 0, 0) LOAD_B(p, 0, 1)
    STAGE_A(p ^ 1, 0, kn)
    BAR();
    WAIT_LGKM();
    __builtin_amdgcn_s_setprio(1);
    MFMA_PAIR(0, 1)
    __builtin_amdgcn_s_setprio(0);
    BAR();
    // ---- phase 2: kk0, n{2,3}; stage B0(next); vmcnt(4) -> kk1 panels landed
    LOAD_B(p, 0, 2) LOAD_B(p, 0, 3)
    STAGE_B(p ^ 1, 0, kn)
    BAR();
    WAIT_LGKM();
    __builtin_amdgcn_s_setprio(1);
    MFMA_PAIR(2, 3)
    __builtin_amdgcn_s_setprio(0);
    VM(4);
    BAR();
    // ---- phase 3: kk1, n{0,1}; stage A1(next)
    LOAD_A(p, 1) LOAD_B(p, 1, 0) LOAD_B(p, 1, 1)
    STAGE_A(p ^ 1, 1, kn)
    BAR();
    WAIT_LGKM();
    __builtin_amdgcn_s_setprio(1);
    MFMA_PAIR(0, 1)
    __builtin_amdgcn_s_setprio(0);
    BAR();
    // ---- phase 4: kk1, n{2,3}; stage B1(next); vmcnt(4) -> next kk0 landed
    LOAD_B(p, 1, 2) LOAD_B(p, 1, 3)
    STAGE_B(p ^ 1, 1, kn)
    BAR();
    WAIT_LGKM();
    __builtin_amdgcn_s_setprio(1);
    MFMA_PAIR(2, 3)
    __builtin_amdgcn_s_setprio(0);
    VM(4);
    BAR();
  }
  // ---- final tile (no staging); kk1 panels need full drain before phase 3
  {
    const int p = (NT - 1) & 1;
    LOAD_A(p, 0) LOAD_B(p, 0, 0) LOAD_B(p, 0, 1)
    BAR();
    WAIT_LGKM();
    __builtin_amdgcn_s_setprio(1);
    MFMA_PAIR(0, 1)
    __builtin_amdgcn_s_setprio(0);
    BAR();
    LOAD_B(p, 0, 2) LOAD_B(p, 0, 3)
    BAR();
    WAIT_LGKM();
    __builtin_amdgcn_s_setprio(1);
    MFMA_PAIR(2, 3)
    __builtin_amdgcn_s_setprio(0);
    VM(0);
    BAR();
    LOAD_A(p, 1) LOAD_B(p, 1, 0) LOAD_B(p, 1, 1)
    BAR();
    WAIT_LGKM();
    __builtin_amdgcn_s_setprio(1);
    MFMA_PAIR(0, 1)
    __builtin_amdgcn_s_setprio(0);
    BAR();
    LOAD_B(p, 1, 2) LOAD_B(p, 1, 3)
    BAR();
    WAIT_LGKM();
    __builtin_amdgcn_s_setprio(1);
    MFMA_PAIR(2, 3)
    __builtin_amdgcn_s_setprio(0);
    BAR();
  }

  if constexpr (!REDUCE) {
#pragma unroll
    for (int m = 0; m < 8; ++m)
#pragma unroll
      for (int n = 0; n < 4; ++n)
#pragma unroll
        for (int j = 0; j < 4; ++j) {
          int gr = m0 + wm * 128 + m * 16 + fq * 4 + j;
          int gc = n0 + wn * 64 + n * 16 + fr;
          C[(size_t)gr * NN + gc] = f2bf(acc[m][n][j]);
        }
  } else {
    if (tid < 256) redrow[tid] = 0.f;
    else redcol[tid - 256] = 0.f;
    __syncthreads();
    // row maxes (offdiag; diag captured exactly once grid-wide)
#pragma unroll
    for (int m = 0; m < 8; ++m)
#pragma unroll
      for (int j = 0; j < 4; ++j) {
        int lr = wm * 128 + m * 16 + fq * 4 + j;
        int prow = m0 + lr;
        float rm = 0.f;
#pragma unroll
        for (int n = 0; n < 4; ++n) {
          int q = n0 + wn * 64 + n * 16 + fr;
          float v = acc[m][n][j];
          if (prow == q) { diag[prow] = v; v = 0.f; }
          rm = fmaxf(rm, v);
        }
        rm = fmaxf(rm, __shfl_xor(rm, 1));
        rm = fmaxf(rm, __shfl_xor(rm, 2));
        rm = fmaxf(rm, __shfl_xor(rm, 4));
        rm = fmaxf(rm, __shfl_xor(rm, 8));
        if (fr == 0) amaxf(&redrow[lr], rm);
      }
    // col maxes
#pragma unroll
    for (int n = 0; n < 4; ++n) {
      int lc = wn * 64 + n * 16 + fr;
      int q = n0 + lc;
      float cm = 0.f;
#pragma unroll
      for (int m = 0; m < 8; ++m)
#pragma unroll
        for (int j = 0; j < 4; ++j) {
          int prow = m0 + wm * 128 + m * 16 + fq * 4 + j;
          float v = acc[m][n][j];
          if (prow == q) v = 0.f;
          cm = fmaxf(cm, v);
        }
      cm = fmaxf(cm, __shfl_xor(cm, 16));
      cm = fmaxf(cm, __shfl_xor(cm, 32));
      if (fq == 0) amaxf(&redcol[lc], cm);
    }
    __syncthreads();
    if (tid < 256) amaxf(&rowmax[m0 + tid], redrow[tid]);
    else amaxf(&colmax[n0 + (tid - 256)], redcol[tid - 256]);
  }
#undef STAGE_A
#undef STAGE_B
#undef LOAD_A
#undef LOAD_B
#undef MFMA_PAIR
#undef BAR
#undef WAIT_LGKM
#undef VM
}

// ---------------------------------------------------------------------------
// LDS-tiled transpose, bf16 4096x4096
__global__ __launch_bounds__(256) void cyc_trans(const unsigned short* __restrict__ in,
                                                 unsigned short* __restrict__ out) {
  __shared__ alignas(16) unsigned short tile[128][136];
  int bx = blockIdx.x & 31, by = blockIdx.x >> 5;
  int r0 = by << 7, c0 = bx << 7;
  int t = threadIdx.x;
#pragma unroll
  for (int i = 0; i < 8; ++i) {
    int lin = i * 256 + t;
    int r = lin >> 4;
    int c8 = (lin & 15) << 3;
    *(uint4*)(&tile[r][c8]) = *(const uint4*)(in + (size_t)(r0 + r) * NN + c0 + c8);
  }
  __syncthreads();
#pragma unroll
  for (int i = 0; i < 8; ++i) {
    int lin = i * 256 + t;
    int c = lin >> 4;
    int r8 = (lin & 15) << 3;
    unsigned short v[8];
#pragma unroll
    for (int j = 0; j < 8; ++j) v[j] = tile[r8 + j][c];
    uint4 o;
    o.x = (unsigned)v[0] | ((unsigned)v[1] << 16);
    o.y = (unsigned)v[2] | ((unsigned)v[3] << 16);
    o.z = (unsigned)v[4] | ((unsigned)v[5] << 16);
    o.w = (unsigned)v[6] | ((unsigned)v[7] << 16);
    *(uint4*)(out + (size_t)(c0 + c) * NN + r0 + r8) = o;
  }
}

// ---------------------------------------------------------------------------
__global__ __launch_bounds__(256) void cyc_rowsum(const unsigned short* __restrict__ X,
                                                  float* __restrict__ rs) {
  int row = blockIdx.x, t = threadIdx.x;
  const uint4* rp = (const uint4*)(X + (size_t)row * NN);
  float s = 0.f;
#pragma unroll
  for (int h = 0; h < 2; ++h) {
    uint4 u = rp[t + h * 256];
    s += __expf(SCALE_F * bflo(u.x)) + __expf(SCALE_F * bfhi(u.x));
    s += __expf(SCALE_F * bflo(u.y)) + __expf(SCALE_F * bfhi(u.y));
    s += __expf(SCALE_F * bflo(u.z)) + __expf(SCALE_F * bfhi(u.z));
    s += __expf(SCALE_F * bflo(u.w)) + __expf(SCALE_F * bfhi(u.w));
  }
  for (int o = 32; o > 0; o >>= 1) s += __shfl_down(s, o);
  __shared__ float red[4];
  if ((t & 63) == 0) red[t >> 6] = s;
  __syncthreads();
  if (t == 0) rs[row] = red[0] + red[1] + red[2] + red[3];
}

// grid (2, 256): block = 2048 cols x 16 rows, thread owns 8 cols
__global__ __launch_bounds__(256) void cyc_colsum(const unsigned short* __restrict__ X,
                                                  float* __restrict__ cs) {
  int t = threadIdx.x;
  int c0 = blockIdx.x * 2048 + t * 8;
  int r0 = blockIdx.y * 16;
  float a[8];
#pragma unroll
  for (int j = 0; j < 8; ++j) a[j] = 0.f;
  for (int r = 0; r < 16; ++r) {
    uint4 u = *(const uint4*)(X + (size_t)(r0 + r) * NN + c0);
    a[0] += __expf(SCALE_F * bflo(u.x)); a[1] += __expf(SCALE_F * bfhi(u.x));
    a[2] += __expf(SCALE_F * bflo(u.y)); a[3] += __expf(SCALE_F * bfhi(u.y));
    a[4] += __expf(SCALE_F * bflo(u.z)); a[5] += __expf(SCALE_F * bfhi(u.z));
    a[6] += __expf(SCALE_F * bflo(u.w)); a[7] += __expf(SCALE_F * bfhi(u.w));
  }
#pragma unroll
  for (int j = 0; j < 8; ++j) atomicAdd(&cs[c0 + j], a[j]);
}

__global__ __launch_bounds__(256) void cyc_inv(float* p) { // 8192 floats (rs+cs)
  int i = blockIdx.x * 256 + threadIdx.x;
  if (i < 2 * NN) p[i] = 1.f / p[i];
}

// A = rowsoftmax, Bc = colsoftmax (bf16), elementwise over X
__global__ __launch_bounds__(256) void cyc_abgen(const unsigned short* __restrict__ X,
                                                 const float* __restrict__ rinv,
                                                 const float* __restrict__ cinv,
                                                 unsigned short* __restrict__ A,
                                                 unsigned short* __restrict__ B) {
  size_t idx = (size_t)blockIdx.x * 256 + threadIdx.x;
  int row = (int)(idx >> 9);
  int c0 = ((int)idx & 511) << 3;
  size_t off = ((size_t)row << 12) + c0;
  uint4 u = *(const uint4*)(X + off);
  float ri = rinv[row];
  float4 ci0 = *(const float4*)(cinv + c0);
  float4 ci1 = *(const float4*)(cinv + c0 + 4);
  float e0 = __expf(SCALE_F * bflo(u.x)), e1 = __expf(SCALE_F * bfhi(u.x));
  float e2 = __expf(SCALE_F * bflo(u.y)), e3 = __expf(SCALE_F * bfhi(u.y));
  float e4 = __expf(SCALE_F * bflo(u.z)), e5 = __expf(SCALE_F * bfhi(u.z));
  float e6 = __expf(SCALE_F * bflo(u.w)), e7 = __expf(SCALE_F * bfhi(u.w));
  uint4 oa, ob;
  oa.x = pack2(e0 * ri, e1 * ri); oa.y = pack2(e2 * ri, e3 * ri);
  oa.z = pack2(e4 * ri, e5 * ri); oa.w = pack2(e6 * ri, e7 * ri);
  ob.x = pack2(e0 * ci0.x, e1 * ci0.y); ob.y = pack2(e2 * ci0.z, e3 * ci0.w);
  ob.z = pack2(e4 * ci1.x, e5 * ci1.y); ob.w = pack2(e6 * ci1.z, e7 * ci1.w);
  *(uint4*)(A + off) = oa;
  *(uint4*)(B + off) = ob;
}

// final scalar: sum over 6 terms of relu(rowmax+M-diag)+relu(colmax+M-diag)
__global__ __launch_bounds__(256) void cyc_loss(const float* __restrict__ arr,
                                                float* __restrict__ out) {
  int t = threadIdx.x;
  float s = 0.f;
  for (int term = 0; term < 6; ++term) {
    const float* base = arr + (size_t)term * 5 * NN;
    const float* rm = base + 2 * NN;
    const float* cm = base + 3 * NN;
    const float* dg = base + 4 * NN;
    for (int i = t; i < NN; i += 256) {
      float d = dg[i];
      s += fmaxf(rm[i] + 0.5f - d, 0.f) + fmaxf(cm[i] + 0.5f - d, 0.f);
    }
  }
  for (int o = 32; o > 0; o >>= 1) s += __shfl_down(s, o);
  __shared__ float red[4];
  if ((t & 63) == 0) red[t >> 6] = s;
  __syncthreads();
  if (t == 0) out[0] = (red[0] + red[1] + red[2] + red[3]) * (1.f / (2.f * NN * 3.f));
}

// ---------------------------------------------------------------------------
static void process_term(const unsigned short* X, int term, unsigned short* Abuf,
                         unsigned short* Bbuf, float* arr, hipStream_t s) {
  float* base = arr + (size_t)term * 5 * NN;
  float* rs = base;
  float* cs = base + NN;
  float* rmax = base + 2 * NN;
  float* cmax = base + 3 * NN;
  float* dg = base + 4 * NN;
  cyc_rowsum<<<NN, 256, 0, s>>>(X, rs);
  cyc_colsum<<<dim3(2, 256), 256, 0, s>>>(X, cs);
  cyc_inv<<<32, 256, 0, s>>>(rs); // inverts rs and cs (contiguous 8192)
  cyc_abgen<<<8192, 256, 0, s>>>(X, rs, cs, Abuf, Bbuf);
  cyc_gemm<NN, true><<<256, 512, 0, s>>>(Abuf, Bbuf, nullptr, rmax, cmax, dg);
}

extern "C" void kernel_launch(void* const* d_in, const int* in_sizes, int n_in,
                              void* d_out, int out_size, void* d_ws, size_t ws_size,
                              hipStream_t stream) {
  (void)in_sizes; (void)n_in; (void)out_size; (void)ws_size;
  const float* f0 = (const float*)d_in[0];
  const float* f1 = (const float*)d_in[1];
  const float* f2 = (const float*)d_in[2];
  char* ws = (char*)d_ws;

  const size_t NF_ELEMS = (size_t)NN * DD;     // 4M shorts = 8 MB
  const size_t S_ELEMS = (size_t)NN * NN;      // 16M shorts = 32 MB
  unsigned short* NF0 = (unsigned short*)ws;
  unsigned short* NF1 = NF0 + NF_ELEMS;
  unsigned short* NF2 = NF1 + NF_ELEMS;
  unsigned short* SA = NF2 + NF_ELEMS; // S01
  unsigned short* SB = SA + S_ELEMS;   // S02
  unsigned short* SC = SB + S_ELEMS;   // S12
  unsigned short* TB = SC + S_ELEMS;   // scratch matrix
  unsigned short* AB = TB + S_ELEMS;   // A (rowsoftmax)
  unsigned short* BB = AB + S_ELEMS;   // Bc (colsoftmax)
  float* arr = (float*)(BB + S_ELEMS); // [6][5][4096] fp32
  float* out = (float*)d_out;

  cyc_zero<<<(6 * 5 * NN + 255) / 256, 256, 0, stream>>>(arr, 6 * 5 * NN);
  cyc_norm<<<NN, 256, 0, stream>>>(f0, NF0);
  cyc_norm<<<NN, 256, 0, stream>>>(f1, NF1);
  cyc_norm<<<NN, 256, 0, stream>>>(f2, NF2);

  // pair similarity matrices
  cyc_gemm<DD, false><<<256, 512, 0, stream>>>(NF0, NF1, SA, nullptr, nullptr, nullptr);
  cyc_gemm<DD, false><<<256, 512, 0, stream>>>(NF0, NF2, SB, nullptr, nullptr, nullptr);
  cyc_gemm<DD, false><<<256, 512, 0, stream>>>(NF1, NF2, SC, nullptr, nullptr, nullptr);

  // pair terms
  process_term(SA, 0, AB, BB, arr, stream);
  process_term(SB, 1, AB, BB, arr, stream);
  process_term(SC, 2, AB, BB, arr, stream);

  // T1 = S02 @ S12^T = NT(SB, SC)
  cyc_gemm<NN, false><<<256, 512, 0, stream>>>(SB, SC, TB, nullptr, nullptr, nullptr);
  process_term(TB, 3, AB, BB, arr, stream);

  // T2 = S01 @ S12 = NT(SA, S12^T): transpose SC -> TB, output into SC slot
  cyc_trans<<<1024, 256, 0, stream>>>(SC, TB);
  cyc_gemm<NN, false><<<256, 512, 0, stream>>>(SA, TB, SC, nullptr, nullptr, nullptr);
  process_term(SC, 4, AB, BB, arr, stream);

  // T3 = S01^T @ S02 = NT(S01^T, S02^T): S10 -> TB, S20 -> AB, out into SA slot
  cyc_trans<<<1024, 256, 0, stream>>>(SA, TB);
  cyc_trans<<<1024, 256, 0, stream>>>(SB, AB);
  cyc_gemm<NN, false><<<256, 512, 0, stream>>>(TB, AB, SA, nullptr, nullptr, nullptr);
  process_term(SA, 5, AB, BB, arr, stream);

  cyc_loss<<<1, 256, 0, stream>>>(arr, out);
}

// Round 6
// 1900.261 us; speedup vs baseline: 1.3490x; 1.0239x over previous
//
#include <hip/hip_runtime.h>

// ---------------------------------------------------------------------------
// CycleS loss on MI355X (gfx950).
// Round 6 (byte-identical resubmit; rounds 4/5 hit GPU acquisition timeouts):
// 256x256 GEMM, BK=64, 8 waves, swizzled [256][32] K-half panels (XOR slot
// swizzle: LDS linear for global_load_lds, pre-swizzled global source +
// swizzled read col), 4 phases/K-tile with 8/4/8/4 ds_read split, counted
// vmcnt(4), setprio; XCD-swizzled grid. Fused aux kernels.
// ---------------------------------------------------------------------------

#define NN 4096
#define DD 1024
static constexpr float SCALE_F = 83.17766166719343f; // ln(4096)/0.1

typedef short  s16x8 __attribute__((ext_vector_type(8)));
typedef float  f32x4 __attribute__((ext_vector_type(4)));

__device__ __forceinline__ float bflo(unsigned w) { return __uint_as_float(w << 16); }
__device__ __forceinline__ float bfhi(unsigned w) { return __uint_as_float(w & 0xffff0000u); }
__device__ __forceinline__ unsigned short f2bf(float f) {
  unsigned u = __float_as_uint(f);
  u += 0x7fffu + ((u >> 16) & 1u);
  return (unsigned short)(u >> 16);
}
__device__ __forceinline__ unsigned pack2(float a, float b) {
  return (unsigned)f2bf(a) | ((unsigned)f2bf(b) << 16);
}
__device__ __forceinline__ void amaxf(float* a, float v) {
  atomicMax((int*)a, __float_as_int(v)); // valid: all values >= 0
}
__device__ __forceinline__ void gl_lds16(const void* g, void* l) {
  __builtin_amdgcn_global_load_lds(
      (const __attribute__((address_space(1))) void*)g,
      (__attribute__((address_space(3))) void*)l, 16, 0, 0);
}

// ---------------------------------------------------------------------------
__global__ __launch_bounds__(256) void cyc_zero(float* p, int n) {
  int i = blockIdx.x * 256 + threadIdx.x;
  if (i < n) p[i] = 0.f;
}

// row-normalize fp32 -> bf16. one block per row, 256 threads * float4
__global__ __launch_bounds__(256) void cyc_norm(const float* __restrict__ in,
                                                unsigned short* __restrict__ out) {
  int row = blockIdx.x, t = threadIdx.x;
  float4 v = *(const float4*)(in + (size_t)row * DD + t * 4);
  float ss = v.x * v.x + v.y * v.y + v.z * v.z + v.w * v.w;
  for (int o = 32; o > 0; o >>= 1) ss += __shfl_down(ss, o);
  __shared__ float red[4];
  if ((t & 63) == 0) red[t >> 6] = ss;
  __syncthreads();
  float tot = red[0] + red[1] + red[2] + red[3];
  float sc = 1.f / fmaxf(sqrtf(tot), 1e-12f);
  uint2 o;
  o.x = pack2(v.x * sc, v.y * sc);
  o.y = pack2(v.z * sc, v.w * sc);
  *(uint2*)(out + (size_t)row * DD + t * 4) = o;
}

// ---------------------------------------------------------------------------
// NT GEMM: C[4096][4096] = A[4096][KT] @ B[4096][KT]^T   (bf16 in, fp32 acc)
// 256x256 tile, BK=64 (two K-halves of 32), 8 waves (2Mx4N), 512 threads.
// LDS panels [256][32] bf16, XOR slot swizzle (slot ^= (row>>1)&3).
// REDUCE: skip C write; emit diag + offdiag row/col max (atomicMax).
template <int KT, bool REDUCE>
__global__ __launch_bounds__(512, 2) void cyc_gemm(
    const unsigned short* __restrict__ A, const unsigned short* __restrict__ B,
    unsigned short* __restrict__ C, float* __restrict__ rowmax,
    float* __restrict__ colmax, float* __restrict__ diag) {
  __shared__ alignas(16) unsigned short LA[2][2][256][32]; // 64 KB
  __shared__ alignas(16) unsigned short LB[2][2][256][32]; // 64 KB
  __shared__ float redrow[256];
  __shared__ float redcol[256];

  constexpr int NT = KT / 64;
  const int orig = blockIdx.x;
  const int bid = ((orig & 7) << 5) | (orig >> 3); // XCD swizzle (256 % 8 == 0)
  const int bm = bid >> 4, bn = bid & 15;
  const int m0 = bm << 8, n0 = bn << 8;
  const int tid = threadIdx.x;
  const int l = tid & 63, w = tid >> 6;
  const int wm = w >> 2, wn = w & 3;
  const int fr = l & 15, fq = l >> 4;
  const int ar = wm * 128 + fr; // + mh*64 + j*16
  const int br = wn * 64 + fr;  // + n*16
  // swizzled read col (elements), per-lane constant: (fq ^ ((row>>1)&3))*8
  const int rc = ((fq ^ ((fr >> 1) & 3)) << 3);
  // staging geometry: per call each thread moves 2 chunks (rows r, r+128)
  const int st_r0 = tid >> 2;            // 0..127
  const int st_r1 = st_r0 + 128;
  const int st_dc = (tid & 3) << 3;      // LDS dest col (linear!)
  const int st_sc = (((tid & 3) ^ ((st_r0 >> 1) & 3)) << 3); // global src col
  // note: ((st_r1>>1)&3) == ((st_r0>>1)&3) since 128>>1 = 64 == 0 (mod 4)

  f32x4 acc[8][4];
#pragma unroll
  for (int m = 0; m < 8; ++m)
#pragma unroll
    for (int n = 0; n < 4; ++n) acc[m][n] = (f32x4){0.f, 0.f, 0.f, 0.f};
  s16x8 af[4], bfv[4];

#define STAGE_A(buf, kk, kbase)                                              \
  {                                                                          \
    gl_lds16(A + (size_t)(m0 + st_r0) * KT + (kbase) + (kk) * 32 + st_sc,    \
             &LA[buf][kk][st_r0][st_dc]);                                    \
    gl_lds16(A + (size_t)(m0 + st_r1) * KT + (kbase) + (kk) * 32 + st_sc,    \
             &LA[buf][kk][st_r1][st_dc]);                                    \
  }
#define STAGE_B(buf, kk, kbase)                                              \
  {                                                                          \
    gl_lds16(B + (size_t)(n0 + st_r0) * KT + (kbase) + (kk) * 32 + st_sc,    \
             &LB[buf][kk][st_r0][st_dc]);                                    \
    gl_lds16(B + (size_t)(n0 + st_r1) * KT + (kbase) + (kk) * 32 + st_sc,    \
             &LB[buf][kk][st_r1][st_dc]);                                    \
  }
#define LOAD_A4(buf, kk, mh)                                                 \
  _Pragma("unroll") for (int j = 0; j < 4; ++j) af[j] =                      \
      *(const s16x8*)&LA[buf][kk][ar + (mh)*64 + j * 16][rc];
#define LOAD_B4(buf, kk)                                                     \
  _Pragma("unroll") for (int n = 0; n < 4; ++n) bfv[n] =                     \
      *(const s16x8*)&LB[buf][kk][br + n * 16][rc];
#define MFMA_Q(mh)                                                           \
  _Pragma("unroll") for (int n = 0; n < 4; ++n)                              \
  _Pragma("unroll") for (int m = 0; m < 4; ++m)                              \
      acc[(mh)*4 + m][n] = __builtin_amdgcn_mfma_f32_16x16x32_bf16(          \
          af[m], bfv[n], acc[(mh)*4 + m][n], 0, 0, 0);
#define BAR() __builtin_amdgcn_s_barrier()
#define WAIT_LGKM() asm volatile("s_waitcnt lgkmcnt(0)" ::: "memory")
#define VM(n) asm volatile("s_waitcnt vmcnt(" #n ")" ::: "memory")
#define PRIO_MFMA(mh)                                                        \
  __builtin_amdgcn_s_setprio(1);                                             \
  MFMA_Q(mh)                                                                 \
  __builtin_amdgcn_s_setprio(0);

  // prologue: stage tile 0 fully (A0,B0,A1,B1)
  STAGE_A(0, 0, 0) STAGE_B(0, 0, 0) STAGE_A(0, 1, 0) STAGE_B(0, 1, 0)
  VM(4); // kk0 panels landed
  BAR();

#pragma unroll 1
  for (int ti = 0; ti < NT - 1; ++ti) {
    const int p = ti & 1;
    const int kn = (ti + 1) * 64;
    // ---- phase 1: kk0 x mh0 (8 ds_reads); stage A0(next)
    LOAD_A4(p, 0, 0) LOAD_B4(p, 0)
    STAGE_A(p ^ 1, 0, kn)
    BAR();
    WAIT_LGKM();
    PRIO_MFMA(0)
    BAR();
    // ---- phase 2: kk0 x mh1 (4 ds_reads, bfv reused); stage B0(next)
    LOAD_A4(p, 0, 1)
    STAGE_B(p ^ 1, 0, kn)
    BAR();
    WAIT_LGKM();
    PRIO_MFMA(1)
    VM(4); // prev kk1 panels landed
    BAR();
    // ---- phase 3: kk1 x mh0 (8 ds_reads); stage A1(next)
    LOAD_A4(p, 1, 0) LOAD_B4(p, 1)
    STAGE_A(p ^ 1, 1, kn)
    BAR();
    WAIT_LGKM();
    PRIO_MFMA(0)
    BAR();
    // ---- phase 4: kk1 x mh1 (4 ds_reads); stage B1(next)
    LOAD_A4(p, 1, 1)
    STAGE_B(p ^ 1, 1, kn)
    BAR();
    WAIT_LGKM();
    PRIO_MFMA(1)
    VM(4); // this-iter kk0 panels landed
    BAR();
  }
  // ---- final tile (no staging)
  {
    const int p = (NT - 1) & 1;
    LOAD_A4(p, 0, 0) LOAD_B4(p, 0)
    BAR();
    WAIT_LGKM();
    PRIO_MFMA(0)
    BAR();
    LOAD_A4(p, 0, 1)
    BAR();
    WAIT_LGKM();
    PRIO_MFMA(1)
    VM(0); // kk1 panels landed
    BAR();
    LOAD_A4(p, 1, 0) LOAD_B4(p, 1)
    BAR();
    WAIT_LGKM();
    PRIO_MFMA(0)
    BAR();
    LOAD_A4(p, 1, 1)
    BAR();
    WAIT_LGKM();
    PRIO_MFMA(1)
    BAR();
  }

  if constexpr (!REDUCE) {
#pragma unroll
    for (int m = 0; m < 8; ++m)
#pragma unroll
      for (int n = 0; n < 4; ++n)
#pragma unroll
        for (int j = 0; j < 4; ++j) {
          int gr = m0 + wm * 128 + m * 16 + fq * 4 + j;
          int gc = n0 + wn * 64 + n * 16 + fr;
          C[(size_t)gr * NN + gc] = f2bf(acc[m][n][j]);
        }
  } else {
    if (tid < 256) redrow[tid] = 0.f;
    else redcol[tid - 256] = 0.f;
    __syncthreads();
    // row maxes (offdiag; diag captured exactly once grid-wide)
#pragma unroll
    for (int m = 0; m < 8; ++m)
#pragma unroll
      for (int j = 0; j < 4; ++j) {
        int lr = wm * 128 + m * 16 + fq * 4 + j;
        int prow = m0 + lr;
        float rm = 0.f;
#pragma unroll
        for (int n = 0; n < 4; ++n) {
          int q = n0 + wn * 64 + n * 16 + fr;
          float v = acc[m][n][j];
          if (prow == q) { diag[prow] = v; v = 0.f; }
          rm = fmaxf(rm, v);
        }
        rm = fmaxf(rm, __shfl_xor(rm, 1));
        rm = fmaxf(rm, __shfl_xor(rm, 2));
        rm = fmaxf(rm, __shfl_xor(rm, 4));
        rm = fmaxf(rm, __shfl_xor(rm, 8));
        if (fr == 0) amaxf(&redrow[lr], rm);
      }
    // col maxes
#pragma unroll
    for (int n = 0; n < 4; ++n) {
      int lc = wn * 64 + n * 16 + fr;
      int q = n0 + lc;
      float cm = 0.f;
#pragma unroll
      for (int m = 0; m < 8; ++m)
#pragma unroll
        for (int j = 0; j < 4; ++j) {
          int prow = m0 + wm * 128 + m * 16 + fq * 4 + j;
          float v = acc[m][n][j];
          if (prow == q) v = 0.f;
          cm = fmaxf(cm, v);
        }
      cm = fmaxf(cm, __shfl_xor(cm, 16));
      cm = fmaxf(cm, __shfl_xor(cm, 32));
      if (fq == 0) amaxf(&redcol[lc], cm);
    }
    __syncthreads();
    if (tid < 256) amaxf(&rowmax[m0 + tid], redrow[tid]);
    else amaxf(&colmax[n0 + (tid - 256)], redcol[tid - 256]);
  }
#undef STAGE_A
#undef STAGE_B
#undef LOAD_A4
#undef LOAD_B4
#undef MFMA_Q
#undef BAR
#undef WAIT_LGKM
#undef VM
#undef PRIO_MFMA
}

// ---------------------------------------------------------------------------
// LDS-tiled transpose, bf16 4096x4096
__global__ __launch_bounds__(256) void cyc_trans(const unsigned short* __restrict__ in,
                                                 unsigned short* __restrict__ out) {
  __shared__ alignas(16) unsigned short tile[128][136];
  int bx = blockIdx.x & 31, by = blockIdx.x >> 5;
  int r0 = by << 7, c0 = bx << 7;
  int t = threadIdx.x;
#pragma unroll
  for (int i = 0; i < 8; ++i) {
    int lin = i * 256 + t;
    int r = lin >> 4;
    int c8 = (lin & 15) << 3;
    *(uint4*)(&tile[r][c8]) = *(const uint4*)(in + (size_t)(r0 + r) * NN + c0 + c8);
  }
  __syncthreads();
#pragma unroll
  for (int i = 0; i < 8; ++i) {
    int lin = i * 256 + t;
    int c = lin >> 4;
    int r8 = (lin & 15) << 3;
    unsigned short v[8];
#pragma unroll
    for (int j = 0; j < 8; ++j) v[j] = tile[r8 + j][c];
    uint4 o;
    o.x = (unsigned)v[0] | ((unsigned)v[1] << 16);
    o.y = (unsigned)v[2] | ((unsigned)v[3] << 16);
    o.z = (unsigned)v[4] | ((unsigned)v[5] << 16);
    o.w = (unsigned)v[6] | ((unsigned)v[7] << 16);
    *(uint4*)(out + (size_t)(c0 + c) * NN + r0 + r8) = o;
  }
}

// ---------------------------------------------------------------------------
// fused row+col sums of exp(scale*X): grid (2,256), 2048 cols x 16 rows/block
__global__ __launch_bounds__(256) void cyc_sums(const unsigned short* __restrict__ X,
                                                float* __restrict__ rs,
                                                float* __restrict__ cs) {
  int t = threadIdx.x;
  int c0 = blockIdx.x * 2048 + t * 8;
  int r0 = blockIdx.y * 16;
  float a[8];
#pragma unroll
  for (int j = 0; j < 8; ++j) a[j] = 0.f;
  for (int r = 0; r < 16; ++r) {
    uint4 u = *(const uint4*)(X + (size_t)(r0 + r) * NN + c0);
    float e0 = __expf(SCALE_F * bflo(u.x)), e1 = __expf(SCALE_F * bfhi(u.x));
    float e2 = __expf(SCALE_F * bflo(u.y)), e3 = __expf(SCALE_F * bfhi(u.y));
    float e4 = __expf(SCALE_F * bflo(u.z)), e5 = __expf(SCALE_F * bfhi(u.z));
    float e6 = __expf(SCALE_F * bflo(u.w)), e7 = __expf(SCALE_F * bfhi(u.w));
    a[0] += e0; a[1] += e1; a[2] += e2; a[3] += e3;
    a[4] += e4; a[5] += e5; a[6] += e6; a[7] += e7;
    float p = ((e0 + e1) + (e2 + e3)) + ((e4 + e5) + (e6 + e7));
    for (int o = 32; o > 0; o >>= 1) p += __shfl_xor(p, o);
    if ((t & 63) == 0) atomicAdd(&rs[r0 + r], p);
  }
#pragma unroll
  for (int j = 0; j < 8; ++j) atomicAdd(&cs[c0 + j], a[j]);
}

// A = rowsoftmax, Bc = colsoftmax (bf16); reciprocals computed inline
__global__ __launch_bounds__(256) void cyc_abgen(const unsigned short* __restrict__ X,
                                                 const float* __restrict__ rsum,
                                                 const float* __restrict__ csum,
                                                 unsigned short* __restrict__ A,
                                                 unsigned short* __restrict__ B) {
  size_t idx = (size_t)blockIdx.x * 256 + threadIdx.x;
  int row = (int)(idx >> 9);
  int c0 = ((int)idx & 511) << 3;
  size_t off = ((size_t)row << 12) + c0;
  uint4 u = *(const uint4*)(X + off);
  float ri = 1.f / rsum[row];
  float4 cs0 = *(const float4*)(csum + c0);
  float4 cs1 = *(const float4*)(csum + c0 + 4);
  float ci0 = 1.f / cs0.x, ci1 = 1.f / cs0.y, ci2 = 1.f / cs0.z, ci3 = 1.f / cs0.w;
  float ci4 = 1.f / cs1.x, ci5 = 1.f / cs1.y, ci6 = 1.f / cs1.z, ci7 = 1.f / cs1.w;
  float e0 = __expf(SCALE_F * bflo(u.x)), e1 = __expf(SCALE_F * bfhi(u.x));
  float e2 = __expf(SCALE_F * bflo(u.y)), e3 = __expf(SCALE_F * bfhi(u.y));
  float e4 = __expf(SCALE_F * bflo(u.z)), e5 = __expf(SCALE_F * bfhi(u.z));
  float e6 = __expf(SCALE_F * bflo(u.w)), e7 = __expf(SCALE_F * bfhi(u.w));
  uint4 oa, ob;
  oa.x = pack2(e0 * ri, e1 * ri); oa.y = pack2(e2 * ri, e3 * ri);
  oa.z = pack2(e4 * ri, e5 * ri); oa.w = pack2(e6 * ri, e7 * ri);
  ob.x = pack2(e0 * ci0, e1 * ci1); ob.y = pack2(e2 * ci2, e3 * ci3);
  ob.z = pack2(e4 * ci4, e5 * ci5); ob.w = pack2(e6 * ci6, e7 * ci7);
  *(uint4*)(A + off) = oa;
  *(uint4*)(B + off) = ob;
}

// partial loss: grid 24 (6 terms x 4 quarters), 256 thr; atomicAdd into accum
__global__ __launch_bounds__(256) void cyc_lossA(const float* __restrict__ arr,
                                                 float* __restrict__ accum) {
  int term = blockIdx.x >> 2, quarter = blockIdx.x & 3;
  int t = threadIdx.x;
  const float* base = arr + (size_t)term * 5 * NN;
  const float* rm = base + 2 * NN;
  const float* cm = base + 3 * NN;
  const float* dg = base + 4 * NN;
  float s = 0.f;
  for (int i = quarter * 1024 + t; i < (quarter + 1) * 1024; i += 256) {
    float d = dg[i];
    s += fmaxf(rm[i] + 0.5f - d, 0.f) + fmaxf(cm[i] + 0.5f - d, 0.f);
  }
  for (int o = 32; o > 0; o >>= 1) s += __shfl_xor(s, o);
  __shared__ float red[4];
  if ((t & 63) == 0) red[t >> 6] = s;
  __syncthreads();
  if (t == 0) atomicAdd(accum, red[0] + red[1] + red[2] + red[3]);
}

__global__ void cyc_lossB(const float* __restrict__ accum, float* __restrict__ out) {
  if (threadIdx.x == 0) out[0] = accum[0] * (1.f / (2.f * NN * 3.f));
}

// ---------------------------------------------------------------------------
static void process_term(const unsigned short* X, int term, unsigned short* Abuf,
                         unsigned short* Bbuf, float* arr, hipStream_t s) {
  float* base = arr + (size_t)term * 5 * NN;
  float* rs = base;
  float* cs = base + NN;
  float* rmax = base + 2 * NN;
  float* cmax = base + 3 * NN;
  float* dg = base + 4 * NN;
  cyc_sums<<<dim3(2, 256), 256, 0, s>>>(X, rs, cs);
  cyc_abgen<<<8192, 256, 0, s>>>(X, rs, cs, Abuf, Bbuf);
  cyc_gemm<NN, true><<<256, 512, 0, s>>>(Abuf, Bbuf, nullptr, rmax, cmax, dg);
}

extern "C" void kernel_launch(void* const* d_in, const int* in_sizes, int n_in,
                              void* d_out, int out_size, void* d_ws, size_t ws_size,
                              hipStream_t stream) {
  (void)in_sizes; (void)n_in; (void)out_size; (void)ws_size;
  const float* f0 = (const float*)d_in[0];
  const float* f1 = (const float*)d_in[1];
  const float* f2 = (const float*)d_in[2];
  char* ws = (char*)d_ws;

  const size_t NF_ELEMS = (size_t)NN * DD;     // 4M shorts = 8 MB
  const size_t S_ELEMS = (size_t)NN * NN;      // 16M shorts = 32 MB
  unsigned short* NF0 = (unsigned short*)ws;
  unsigned short* NF1 = NF0 + NF_ELEMS;
  unsigned short* NF2 = NF1 + NF_ELEMS;
  unsigned short* SA = NF2 + NF_ELEMS; // S01
  unsigned short* SB = SA + S_ELEMS;   // S02
  unsigned short* SC = SB + S_ELEMS;   // S12
  unsigned short* TB = SC + S_ELEMS;   // scratch matrix
  unsigned short* AB = TB + S_ELEMS;   // A (rowsoftmax)
  unsigned short* BB = AB + S_ELEMS;   // Bc (colsoftmax)
  float* arr = (float*)(BB + S_ELEMS); // [6][5][4096] fp32 + accum
  float* accum = arr + 6 * 5 * NN;
  float* out = (float*)d_out;

  cyc_zero<<<(6 * 5 * NN + 256 + 255) / 256, 256, 0, stream>>>(arr, 6 * 5 * NN + 256);
  cyc_norm<<<NN, 256, 0, stream>>>(f0, NF0);
  cyc_norm<<<NN, 256, 0, stream>>>(f1, NF1);
  cyc_norm<<<NN, 256, 0, stream>>>(f2, NF2);

  // pair similarity matrices
  cyc_gemm<DD, false><<<256, 512, 0, stream>>>(NF0, NF1, SA, nullptr, nullptr, nullptr);
  cyc_gemm<DD, false><<<256, 512, 0, stream>>>(NF0, NF2, SB, nullptr, nullptr, nullptr);
  cyc_gemm<DD, false><<<256, 512, 0, stream>>>(NF1, NF2, SC, nullptr, nullptr, nullptr);

  // pair terms
  process_term(SA, 0, AB, BB, arr, stream);
  process_term(SB, 1, AB, BB, arr, stream);
  process_term(SC, 2, AB, BB, arr, stream);

  // T1 = S02 @ S12^T = NT(SB, SC)
  cyc_gemm<NN, false><<<256, 512, 0, stream>>>(SB, SC, TB, nullptr, nullptr, nullptr);
  process_term(TB, 3, AB, BB, arr, stream);

  // T2 = S01 @ S12 = NT(SA, S12^T): transpose SC -> TB, output into SC slot
  cyc_trans<<<1024, 256, 0, stream>>>(SC, TB);
  cyc_gemm<NN, false><<<256, 512, 0, stream>>>(SA, TB, SC, nullptr, nullptr, nullptr);
  process_term(SC, 4, AB, BB, arr, stream);

  // T3 = S01^T @ S02 = NT(S01^T, S02^T): S10 -> TB, S20 -> AB, out into SA slot
  cyc_trans<<<1024, 256, 0, stream>>>(SA, TB);
  cyc_trans<<<1024, 256, 0, stream>>>(SB, AB);
  cyc_gemm<NN, false><<<256, 512, 0, stream>>>(TB, AB, SA, nullptr, nullptr, nullptr);
  process_term(SA, 5, AB, BB, arr, stream);

  cyc_lossA<<<24, 256, 0, stream>>>(arr, accum);
  cyc_lossB<<<1, 64, 0, stream>>>(accum, out);
}